// Round 21
// baseline (135.195 us; speedup 1.0000x reference)
//
#include <hip/hip_runtime.h>
#include <cstdint>

// Problem constants
#define GQ 4
#define KQ 1024
#define DQ 256     // = GQ * dq
#define dq 64
#define NQ 32768   // B*S = 8*4096
#define DECAYF 0.99f
#define EPSF 1e-5f

// Output flat offsets (floats)
#define OFF_ZQ    0
#define OFF_IND   8388608
#define OFF_EMB   8519680
#define OFF_CS    8781824
#define OFF_AVG   8785920

// Workspace layout (bytes)
#define WS_IND   0              // int32 [GQ][NQ]  (transposed ind)
#define WS_E2    524288         // float [GQ][KQ]
#define WS_EH    540672         // ushort(bf16) fragment-ordered embed hi
#define WS_EL    1064960        // ushort(bf16) fragment-ordered embed lo
#define WS_CTR   1589264        // int
#define WS_LIST  1589280        // int2 [CAP]
#define CAP      16384
#define WS_E2D   1720352        // double [GQ*KQ]
#define WS_TOT   1753120        // float [GQ]
#define WS_PART  1753344        // int32 [8][GQ*KQ][64] partial fixed-point sums (8 MB)
#define WS_PCNT  10141952       // int32 [8][GQ*KQ] partial counts (128 KB)

#define MARGIN 0.01f
#define FPS 65536.0f            // 2^16 fixed-point (order-free exact adds)

#define MBLK 128   // rows per block (4 waves x 32 rows)

typedef __attribute__((ext_vector_type(8))) short bf16x8;
typedef __attribute__((ext_vector_type(4))) float f32x4;
typedef __attribute__((ext_vector_type(16))) float f32x16;

// f32 -> bf16 hi/lo split of 8 values, scaled by 2 (exact exponent shift)
__device__ __forceinline__ void split8_2x(float4 u, float4 v, bf16x8& h, bf16x8& l) {
    float f[8] = {u.x, u.y, u.z, u.w, v.x, v.y, v.z, v.w};
#pragma unroll
    for (int j = 0; j < 8; ++j) {
        float s = f[j] * 2.0f;
        uint32_t b = __float_as_uint(s);
        uint32_t hb = b & 0xffff0000u;
        float r = s - __uint_as_float(hb);
        uint32_t rb = __float_as_uint(r);
        h[j] = (short)(hb >> 16);
        l[j] = (short)((rb + 0x7fffu + ((rb >> 16) & 1u)) >> 16);
    }
}

// ---- prep: e2 (f32+f64); embed split bf16 hi/lo in 32x32x16 FRAGMENT ORDER;
//      tot[g]; ctr=0.
// 32x32 B-frag: lane = khalf*32 + (col&31) reads 8 elems k = kb*16 + khalf*8 + j
// of col; elem addr = g*65536 + ch*4096 + kb*1024 + n*512 + lane*8 + j
// thread t = (row, f): f = j_full>>3 -> kb = f>>1, khalf = f&1.
__global__ void k_prep(const float* __restrict__ embed, const float* __restrict__ cs,
                       float* __restrict__ e2, double* __restrict__ e2d,
                       ushort* __restrict__ eh, ushort* __restrict__ el,
                       float* __restrict__ tot, int* __restrict__ ctr) {
    __shared__ double red[256];
    int t = blockIdx.x * 256 + threadIdx.x;   // 0..32767
    int row = t >> 3;                         // g*1024 + k
    int f = t & 7;
    int g = row >> 10, k = row & 1023;
    int ch = k >> 6, co = k & 63;

    const float4* p = reinterpret_cast<const float4*>(embed + (size_t)row * dq + f * 8);
    float4 u = p[0], v = p[1];
    float fv[8] = {u.x, u.y, u.z, u.w, v.x, v.y, v.z, v.w};
    bf16x8 h, l;
    double s = 0.0;
#pragma unroll
    for (int jj = 0; jj < 8; ++jj) {
        float x = fv[jj];
        s = fma((double)x, (double)x, s);
        uint32_t b = __float_as_uint(x);
        uint32_t hb = (b + 0x7fffu + ((b >> 16) & 1u)) & 0xffff0000u;
        float r = x - __uint_as_float(hb);
        uint32_t rb = __float_as_uint(r);
        h[jj] = (short)(hb >> 16);
        l[jj] = (short)((rb + 0x7fffu + ((rb >> 16) & 1u)) >> 16);
    }
    size_t addr = (size_t)g * 65536 + (size_t)ch * 4096 + (size_t)(f >> 1) * 1024
                + (size_t)(co >> 5) * 512 + (size_t)((f & 1) * 32 + (co & 31)) * 8;
    *reinterpret_cast<bf16x8*>(eh + addr) = h;
    *reinterpret_cast<bf16x8*>(el + addr) = l;
    s += __shfl_xor(s, 1, 64);
    s += __shfl_xor(s, 2, 64);
    s += __shfl_xor(s, 4, 64);
    if (f == 0) { e2[row] = (float)s; e2d[row] = s; }

    if (blockIdx.x < 4) {
        int gg = blockIdx.x;
        const float4* c4 = reinterpret_cast<const float4*>(cs + gg * KQ);
        float4 cv = c4[threadIdx.x];
        red[threadIdx.x] = (double)cv.x + (double)cv.y + (double)cv.z + (double)cv.w;
        __syncthreads();
        for (int off = 128; off > 0; off >>= 1) {
            if (threadIdx.x < off) red[threadIdx.x] += red[threadIdx.x + off];
            __syncthreads();
        }
        if (threadIdx.x == 0) {
            tot[gg] = (float)((double)DECAYF * red[0] + (1.0 - (double)DECAYF) * (double)NQ);
            if (gg == 0) *ctr = 0;
        }
    }
}

// ---- MFMA scores: 32x32x16 MFMA (half the issue slots vs 16x16x32).
//      Same dbuf staging / barriers / margin / fused outputs as R17/R20. ----
__launch_bounds__(256)
__global__ void k_scores_mfma(const float* __restrict__ x,
                              const ushort* __restrict__ eh,
                              const ushort* __restrict__ el,
                              const float* __restrict__ e2,
                              const float* __restrict__ embed,
                              int* __restrict__ ind_t,
                              float* __restrict__ zq,
                              float* __restrict__ ind_out,
                              int* __restrict__ ctr, int2* __restrict__ list) {
    int g = blockIdx.y;
    int n0 = blockIdx.x * MBLK;
    int tid = threadIdx.x;
    int wid = tid >> 6;          // 0..3
    int lane = tid & 63;
    int l31 = lane & 31, lhi = lane >> 5;

    __shared__ ushort lds[2][8192];   // 32 KB; ckk overlays buf0 post-loop

    // A fragments: row = n0 + wid*32 + l31, k = kb*16 + lhi*8 + j (x2 scale)
    bf16x8 ah[4], al[4];
#pragma unroll
    for (int kb = 0; kb < 4; ++kb) {
        const float4* p = reinterpret_cast<const float4*>(
            x + (size_t)(n0 + wid * 32 + l31) * DQ + g * dq + kb * 16 + lhi * 8);
        split8_2x(p[0], p[1], ah[kb], al[kb]);
    }

    const ushort* ehg = eh + (size_t)g * 65536;
    const ushort* elg = el + (size_t)g * 65536;
    const float*  e2g = e2 + (size_t)g * KQ;

    float m1[16], m2[16];
    int   k1[16];
#pragma unroll
    for (int r = 0; r < 16; ++r) { m1[r] = -3.4e38f; m2[r] = -3.4e38f; k1[r] = 0; }

    int wu = wid * 512;
#define STAGE(b, ch)                                                               \
    do {                                                                           \
        const ushort* s0_ = ehg + (ch) * 4096 + tid * 8;                           \
        const ushort* s1_ = elg + (ch) * 4096 + tid * 8;                           \
        __builtin_amdgcn_global_load_lds(s0_,        &lds[b][wu],        16, 0, 0);\
        __builtin_amdgcn_global_load_lds(s0_ + 2048, &lds[b][2048 + wu], 16, 0, 0);\
        __builtin_amdgcn_global_load_lds(s1_,        &lds[b][4096 + wu], 16, 0, 0);\
        __builtin_amdgcn_global_load_lds(s1_ + 2048, &lds[b][6144 + wu], 16, 0, 0);\
    } while (0)

    float e2cur[2];
    e2cur[0] = e2g[l31];
    e2cur[1] = e2g[32 + l31];

    STAGE(0, 0);
    int cur = 0;

#pragma unroll 1
    for (int ch = 0; ch < 16; ++ch) {
        int cb = ch * 64;
        __syncthreads();                    // drains vmcnt -> lds[cur] ready
        if (ch < 15) STAGE(cur ^ 1, ch + 1);

        float e2nxt[2];
        if (ch < 15) {
            e2nxt[0] = e2g[cb + 64 + l31];
            e2nxt[1] = e2g[cb + 96 + l31];
        }

        f32x16 acc[2];
#pragma unroll
        for (int n = 0; n < 2; ++n)
#pragma unroll
            for (int r = 0; r < 16; ++r) acc[n][r] = -e2cur[n];

#pragma unroll
        for (int kb = 0; kb < 4; ++kb) {
            bf16x8 bh[2], bl[2];
            int base = kb * 1024 + lane * 8;
            bh[0] = *reinterpret_cast<const bf16x8*>(&lds[cur][base]);
            bh[1] = *reinterpret_cast<const bf16x8*>(&lds[cur][base + 512]);
            bl[0] = *reinterpret_cast<const bf16x8*>(&lds[cur][4096 + base]);
            bl[1] = *reinterpret_cast<const bf16x8*>(&lds[cur][4096 + base + 512]);
#pragma unroll
            for (int n = 0; n < 2; ++n) {
                acc[n] = __builtin_amdgcn_mfma_f32_32x32x16_bf16(ah[kb], bh[n], acc[n], 0, 0, 0);
                acc[n] = __builtin_amdgcn_mfma_f32_32x32x16_bf16(ah[kb], bl[n], acc[n], 0, 0, 0);
                acc[n] = __builtin_amdgcn_mfma_f32_32x32x16_bf16(al[kb], bh[n], acc[n], 0, 0, 0);
            }
        }

        // epilogue: s = acc (e2, 2x folded); top-2 per reg r (row-local)
#pragma unroll
        for (int n = 0; n < 2; ++n) {
            int col = cb + n * 32 + l31;
#pragma unroll
            for (int r = 0; r < 16; ++r) {
                float s = acc[n][r];
                bool gt = s > m1[r];
                m2[r] = __builtin_amdgcn_fmed3f(s, m1[r], m2[r]);
                k1[r] = gt ? col : k1[r];
                m1[r] = fmaxf(m1[r], s);
            }
        }
        e2cur[0] = e2nxt[0];
        e2cur[1] = e2nxt[1];
        cur ^= 1;
    }
#undef STAGE

    int* ckk = reinterpret_cast<int*>(&lds[0][0]);   // overlays dead buf0

    // cross-lane reduce over the 32 col-lanes (same rows share lane>>5)
#pragma unroll
    for (int r = 0; r < 16; ++r) {
        float a1 = m1[r], a2 = m2[r];
        int ak = k1[r];
#pragma unroll
        for (int d = 1; d < 32; d <<= 1) {
            float o1 = __shfl_xor(a1, d, 64);
            float o2 = __shfl_xor(a2, d, 64);
            int   ok = __shfl_xor(ak, d, 64);
            bool sw = (o1 > a1) || (o1 == a1 && ok < ak);
            float big = sw ? o1 : a1;
            int bigk = sw ? ok : ak;
            float small = sw ? a1 : o1;
            a2 = fmaxf(fmaxf(a2, o2), small);
            a1 = big; ak = bigk;
        }
        if (l31 == 0) {
            int rloc = (r & 3) + 8 * (r >> 2) + 4 * lhi;   // 0..31 within wave
            int row = n0 + wid * 32 + rloc;
            ckk[wid * 32 + rloc] = ak;
            ind_t[(size_t)g * NQ + row] = ak;
            if (a1 - a2 < MARGIN) {
                int idx = atomicAdd(ctr, 1);
                if (idx < CAP) list[idx] = make_int2(row, g);
            }
        }
    }
    __syncthreads();

    if (lane < 32) {
        int row = n0 + wid * 32 + lane;
        ind_out[(size_t)row * GQ + g] = (float)ckk[wid * 32 + lane];
    }
#pragma unroll 4
    for (int rr = 0; rr < 32; ++rr) {
        int k = ckk[wid * 32 + rr];
        float v = embed[((size_t)(g * KQ + k)) * dq + lane];
        zq[(size_t)(n0 + wid * 32 + rr) * DQ + g * dq + lane] = v;
    }
}

// ---- f64 recheck (separate, load-balanced, vectorized) ----
__launch_bounds__(256)
__global__ void k_recheck(const float* __restrict__ x, const float* __restrict__ embed,
                          const double* __restrict__ e2d,
                          const int* __restrict__ ctr, const int2* __restrict__ list,
                          int* __restrict__ ind_t, float* __restrict__ zq,
                          float* __restrict__ ind_out) {
    __shared__ double sv[256];
    __shared__ int si[256];
    int nitems = *ctr;
    if (nitems > CAP) nitems = CAP;
    for (int it = blockIdx.x; it < nitems; it += gridDim.x) {
        int2 q = list[it];
        int n = q.x, g = q.y;
        const float4* xr4 = reinterpret_cast<const float4*>(x + (size_t)n * DQ + g * dq);
        float4 xr[16];
#pragma unroll
        for (int j = 0; j < 16; ++j) xr[j] = xr4[j];
        double best = -1e300;
        int bk = KQ;
        for (int k = threadIdx.x; k < KQ; k += 256) {
            const float4* er = reinterpret_cast<const float4*>(embed + ((size_t)g * KQ + k) * dq);
            double dot = 0.0;
#pragma unroll
            for (int j = 0; j < 16; ++j) {
                float4 e4 = er[j];
                dot = fma((double)xr[j].x, (double)e4.x, dot);
                dot = fma((double)xr[j].y, (double)e4.y, dot);
                dot = fma((double)xr[j].z, (double)e4.z, dot);
                dot = fma((double)xr[j].w, (double)e4.w, dot);
            }
            double s = 2.0 * dot - e2d[g * KQ + k];
            if (s > best || (s == best && k < bk)) { best = s; bk = k; }
        }
        sv[threadIdx.x] = best; si[threadIdx.x] = bk;
        __syncthreads();
        for (int off = 128; off > 0; off >>= 1) {
            if (threadIdx.x < off) {
                double ov = sv[threadIdx.x + off]; int oi = si[threadIdx.x + off];
                if (ov > sv[threadIdx.x] || (ov == sv[threadIdx.x] && oi < si[threadIdx.x])) {
                    sv[threadIdx.x] = ov; si[threadIdx.x] = oi;
                }
            }
            __syncthreads();
        }
        int kbest = si[0];
        if (threadIdx.x == 0) {
            ind_t[(size_t)g * NQ + n] = kbest;
            ind_out[(size_t)n * GQ + g] = (float)kbest;
        }
        if (threadIdx.x < dq)
            zq[(size_t)n * DQ + g * dq + threadIdx.x] =
                embed[((size_t)g * KQ + kbest) * dq + threadIdx.x];
        __syncthreads();
    }
}

// ---- segsum v4b: 32 bins/block, 8-way N-split, 4-batched drain (R17, proven) ----
#define SBINS 32
__launch_bounds__(256)
__global__ void k_segsum4(const float* __restrict__ x, const int* __restrict__ ind_t,
                          int* __restrict__ partial, int* __restrict__ pcnt) {
    __shared__ int lacc[SBINS][64];   // 8 KB
    __shared__ int lcnt[SBINS];
    __shared__ int queue[4][128];

    int bid = blockIdx.x;             // [0,1024): g(2) | grp(5) | split(3)
    int g = bid >> 8;
    int grp = (bid >> 3) & 31;
    int split = bid & 7;
    int kbase = grp * SBINS;
    int tid = threadIdx.x, wid = tid >> 6, lane = tid & 63;

    for (int i = tid; i < SBINS * 64; i += 256) ((int*)lacc)[i] = 0;
    if (tid < SBINS) lcnt[tid] = 0;
    __syncthreads();

    const int* ip = ind_t + (size_t)g * NQ;
    const float* xg = x + g * dq;
    int nbase = split * 4096 + wid * 1024;
    int wqn = 0;

#define DRAIN4                                                                      \
    do {                                                                            \
        int nq4 = wqn & ~3;                                                         \
        for (int q = 0; q < nq4; q += 4) {                                          \
            int ea = queue[wid][q],     eb = queue[wid][q + 1];                     \
            int ec = queue[wid][q + 2], ed = queue[wid][q + 3];                     \
            float va = xg[(size_t)(ea & 0xfffff) * DQ + lane];                      \
            float vb = xg[(size_t)(eb & 0xfffff) * DQ + lane];                      \
            float vc = xg[(size_t)(ec & 0xfffff) * DQ + lane];                      \
            float vd = xg[(size_t)(ed & 0xfffff) * DQ + lane];                      \
            atomicAdd(&lacc[ea >> 20][lane], __float2int_rn(va * FPS));             \
            atomicAdd(&lacc[eb >> 20][lane], __float2int_rn(vb * FPS));             \
            atomicAdd(&lacc[ec >> 20][lane], __float2int_rn(vc * FPS));             \
            atomicAdd(&lacc[ed >> 20][lane], __float2int_rn(vd * FPS));             \
            if (lane == 0) {                                                        \
                atomicAdd(&lcnt[ea >> 20], 1); atomicAdd(&lcnt[eb >> 20], 1);       \
                atomicAdd(&lcnt[ec >> 20], 1); atomicAdd(&lcnt[ed >> 20], 1);       \
            }                                                                       \
        }                                                                           \
        for (int q = nq4; q < wqn; ++q) {                                           \
            int e = queue[wid][q];                                                  \
            float v = xg[(size_t)(e & 0xfffff) * DQ + lane];                        \
            atomicAdd(&lacc[e >> 20][lane], __float2int_rn(v * FPS));               \
            if (lane == 0) atomicAdd(&lcnt[e >> 20], 1);                            \
        }                                                                           \
        wqn = 0;                                                                    \
    } while (0)

    for (int c = 0; c < 1024; c += 64) {
        int n = nbase + c + lane;
        int d = ip[n] - kbase;
        bool hit = (unsigned)d < (unsigned)SBINS;
        unsigned long long mask = __ballot(hit);
        if (hit) {
            int pos = wqn + __popcll(mask & ((1ull << lane) - 1ull));
            queue[wid][pos] = (d << 20) | n;
        }
        wqn += __popcll(mask);
        if (wqn >= 64) DRAIN4;
    }
    DRAIN4;
#undef DRAIN4
    __syncthreads();

    int base = split * (GQ * KQ) + g * KQ + kbase;
    for (int i = tid; i < SBINS * 64; i += 256) {
        int b = i >> 6, l = i & 63;
        partial[(size_t)(base + b) * 64 + l] = lacc[b][l];
    }
    if (tid < SBINS) pcnt[base + tid] = lcnt[tid];
}

// ---- final: combine 8 partials; out_cs / out_avg / out_embed ----
__global__ void k_final(const int* __restrict__ partial, const int* __restrict__ pcnt,
                        const float* __restrict__ embed_avg, const float* __restrict__ cs,
                        const float* __restrict__ tot,
                        float* __restrict__ out_cs, float* __restrict__ out_avg,
                        float* __restrict__ out_embed) {
    int t = blockIdx.x * 256 + threadIdx.x;   // 0..262143
    int gk = t >> 6, l = t & 63, g = gk >> 10;
    const int GK = GQ * KQ;
    int s = 0, c = 0;
#pragma unroll
    for (int sp = 0; sp < 8; ++sp) {
        s += partial[((size_t)sp * GK + gk) * 64 + l];
        c += pcnt[sp * GK + gk];
    }
    float a = (float)s * (1.0f / FPS);
    float nea = DECAYF * embed_avg[t] + (1.0f - DECAYF) * a;
    out_avg[t] = nea;
    float ncs = DECAYF * cs[gk] + (1.0f - DECAYF) * (float)c;
    if (l == 0) out_cs[gk] = ncs;
    double tt = (double)tot[g];
    double sm = ((double)ncs + (double)EPSF) / (tt + (double)KQ * (double)EPSF) * tt;
    out_embed[t] = nea / (float)sm;
}

extern "C" void kernel_launch(void* const* d_in, const int* in_sizes, int n_in,
                              void* d_out, int out_size, void* d_ws, size_t ws_size,
                              hipStream_t stream) {
    const float* x         = (const float*)d_in[0];
    const float* embed     = (const float*)d_in[1];
    const float* embed_avg = (const float*)d_in[2];
    const float* cs        = (const float*)d_in[3];
    float* out = (float*)d_out;
    float* zq        = out + OFF_ZQ;
    float* ind_out   = out + OFF_IND;
    float* out_embed = out + OFF_EMB;
    float* out_cs    = out + OFF_CS;
    float* out_avg   = out + OFF_AVG;

    char* ws = (char*)d_ws;
    int*    ind_t = (int*)(ws + WS_IND);
    float*  e2    = (float*)(ws + WS_E2);
    ushort* eh    = (ushort*)(ws + WS_EH);
    ushort* el    = (ushort*)(ws + WS_EL);
    int*    ctr   = (int*)(ws + WS_CTR);
    int2*   list  = (int2*)(ws + WS_LIST);
    double* e2d   = (double*)(ws + WS_E2D);
    float*  tot   = (float*)(ws + WS_TOT);
    int*    part  = (int*)(ws + WS_PART);
    int*    pcnt  = (int*)(ws + WS_PCNT);

    k_prep<<<128, 256, 0, stream>>>(embed, cs, e2, e2d, eh, el, tot, ctr);
    dim3 g1(NQ / MBLK, GQ);
    k_scores_mfma<<<g1, 256, 0, stream>>>(x, eh, el, e2, embed, ind_t, zq, ind_out, ctr, list);
    k_recheck<<<256, 256, 0, stream>>>(x, embed, e2d, ctr, list, ind_t, zq, ind_out);
    k_segsum4<<<1024, 256, 0, stream>>>(x, ind_t, part, pcnt);
    k_final<<<(GQ * KQ * dq) / 256, 256, 0, stream>>>(part, pcnt, embed_avg, cs, tot,
                                                      out_cs, out_avg, out_embed);
}

// Round 22
// 124.606 us; speedup vs baseline: 1.0850x; 1.0850x over previous
//
#include <hip/hip_runtime.h>
#include <cstdint>

// Problem constants
#define GQ 4
#define KQ 1024
#define DQ 256     // = GQ * dq
#define dq 64
#define NQ 32768   // B*S = 8*4096
#define DECAYF 0.99f
#define EPSF 1e-5f

// Output flat offsets (floats)
#define OFF_ZQ    0
#define OFF_IND   8388608
#define OFF_EMB   8519680
#define OFF_CS    8781824
#define OFF_AVG   8785920

// Workspace layout (bytes)
#define WS_IND   0              // int32 [GQ][NQ]  (transposed ind)
#define WS_E2    524288         // float [GQ][KQ]
#define WS_EH    540672         // ushort(bf16) fragment-ordered embed hi
#define WS_EL    1064960        // ushort(bf16) fragment-ordered embed lo
#define WS_CTR   1589264        // int
#define WS_LIST  1589280        // int2 [CAP]
#define CAP      16384
#define WS_E2D   1720352        // double [GQ*KQ]
#define WS_TOT   1753120        // float [GQ]
#define WS_PART  1753344        // int32 [8][GQ*KQ][64] partial fixed-point sums (8 MB)
#define WS_PCNT  10141952       // int32 [8][GQ*KQ] partial counts (128 KB)

#define MARGIN 0.01f
#define FPS 65536.0f            // 2^16 fixed-point (order-free exact adds)

#define MBLK 128   // rows per block (4 waves x 32 rows) — R17/R20-verified balance point

typedef __attribute__((ext_vector_type(8))) short bf16x8;
typedef __attribute__((ext_vector_type(4))) float f32x4;

// f32 -> bf16 hi/lo split of 8 values, scaled by 2 (exact exponent shift)
__device__ __forceinline__ void split8_2x(float4 u, float4 v, bf16x8& h, bf16x8& l) {
    float f[8] = {u.x, u.y, u.z, u.w, v.x, v.y, v.z, v.w};
#pragma unroll
    for (int j = 0; j < 8; ++j) {
        float s = f[j] * 2.0f;
        uint32_t b = __float_as_uint(s);
        uint32_t hb = b & 0xffff0000u;
        float r = s - __uint_as_float(hb);
        uint32_t rb = __float_as_uint(r);
        h[j] = (short)(hb >> 16);
        l[j] = (short)((rb + 0x7fffu + ((rb >> 16) & 1u)) >> 16);
    }
}

// ---- prep: e2 (f32+f64); embed split bf16 hi/lo FRAGMENT ORDER; tot[g]; ctr=0 ----
__global__ void k_prep(const float* __restrict__ embed, const float* __restrict__ cs,
                       float* __restrict__ e2, double* __restrict__ e2d,
                       ushort* __restrict__ eh, ushort* __restrict__ el,
                       float* __restrict__ tot, int* __restrict__ ctr) {
    __shared__ double red[256];
    int t = blockIdx.x * 256 + threadIdx.x;   // 0..32767
    int row = t >> 3;                         // g*1024 + k
    int f = t & 7;
    int c = f >> 2, l4 = f & 3;
    int g = row >> 10, k = row & 1023;
    int ch = k >> 6, co = k & 63;

    const float4* p = reinterpret_cast<const float4*>(embed + (size_t)row * dq + f * 8);
    float4 u = p[0], v = p[1];
    float fv[8] = {u.x, u.y, u.z, u.w, v.x, v.y, v.z, v.w};
    bf16x8 h, l;
    double s = 0.0;
#pragma unroll
    for (int jj = 0; jj < 8; ++jj) {
        float x = fv[jj];
        s = fma((double)x, (double)x, s);
        uint32_t b = __float_as_uint(x);
        uint32_t hb = (b + 0x7fffu + ((b >> 16) & 1u)) & 0xffff0000u;
        float r = x - __uint_as_float(hb);
        uint32_t rb = __float_as_uint(r);
        h[jj] = (short)(hb >> 16);
        l[jj] = (short)((rb + 0x7fffu + ((rb >> 16) & 1u)) >> 16);
    }
    size_t addr = (size_t)g * 65536 + (size_t)ch * 4096 + (size_t)(c * 4 + l4) * 512 + co * 8;
    *reinterpret_cast<bf16x8*>(eh + addr) = h;
    *reinterpret_cast<bf16x8*>(el + addr) = l;
    s += __shfl_xor(s, 1, 64);
    s += __shfl_xor(s, 2, 64);
    s += __shfl_xor(s, 4, 64);
    if (f == 0) { e2[row] = (float)s; e2d[row] = s; }

    if (blockIdx.x < 4) {
        int gg = blockIdx.x;
        const float4* c4 = reinterpret_cast<const float4*>(cs + gg * KQ);
        float4 cv = c4[threadIdx.x];
        red[threadIdx.x] = (double)cv.x + (double)cv.y + (double)cv.z + (double)cv.w;
        __syncthreads();
        for (int off = 128; off > 0; off >>= 1) {
            if (threadIdx.x < off) red[threadIdx.x] += red[threadIdx.x + off];
            __syncthreads();
        }
        if (threadIdx.x == 0) {
            tot[gg] = (float)((double)DECAYF * red[0] + (1.0 - (double)DECAYF) * (double)NQ);
            if (gg == 0) *ctr = 0;
        }
    }
}

// ---- MFMA scores (R17/R20-verified): LDS dbuf staging + fused argmax + zq/ind ----
__launch_bounds__(256)
__global__ void k_scores_mfma(const float* __restrict__ x,
                              const ushort* __restrict__ eh,
                              const ushort* __restrict__ el,
                              const float* __restrict__ e2,
                              const float* __restrict__ embed,
                              int* __restrict__ ind_t,
                              float* __restrict__ zq,
                              float* __restrict__ ind_out,
                              int* __restrict__ ctr, int2* __restrict__ list) {
    int g = blockIdx.y;
    int n0 = blockIdx.x * MBLK;
    int tid = threadIdx.x;
    int wid = tid >> 6;          // 0..3
    int lane = tid & 63;
    int l15 = lane & 15, l4 = lane >> 4;

    __shared__ ushort lds[2][8192];   // 32 KB; ckk overlays buf0 post-loop

    bf16x8 ah[2][2], al[2][2];
#pragma unroll
    for (int m = 0; m < 2; ++m)
#pragma unroll
        for (int c = 0; c < 2; ++c) {
            const float4* p = reinterpret_cast<const float4*>(
                x + (size_t)(n0 + wid * 32 + m * 16 + l15) * DQ + g * dq + c * 32 + l4 * 8);
            split8_2x(p[0], p[1], ah[m][c], al[m][c]);
        }

    const ushort* ehg = eh + (size_t)g * 65536;
    const ushort* elg = el + (size_t)g * 65536;
    const float*  e2g = e2 + (size_t)g * KQ;

    float m1[2][4], m2[2][4];
    int   k1[2][4];
#pragma unroll
    for (int m = 0; m < 2; ++m)
#pragma unroll
        for (int r = 0; r < 4; ++r) { m1[m][r] = -3.4e38f; m2[m][r] = -3.4e38f; k1[m][r] = 0; }

    int wu = wid * 512;
#define STAGE(b, ch)                                                               \
    do {                                                                           \
        const ushort* s0_ = ehg + (ch) * 4096 + tid * 8;                           \
        const ushort* s1_ = elg + (ch) * 4096 + tid * 8;                           \
        __builtin_amdgcn_global_load_lds(s0_,        &lds[b][wu],        16, 0, 0);\
        __builtin_amdgcn_global_load_lds(s0_ + 2048, &lds[b][2048 + wu], 16, 0, 0);\
        __builtin_amdgcn_global_load_lds(s1_,        &lds[b][4096 + wu], 16, 0, 0);\
        __builtin_amdgcn_global_load_lds(s1_ + 2048, &lds[b][6144 + wu], 16, 0, 0);\
    } while (0)

    float e2cur[4];
#pragma unroll
    for (int n = 0; n < 4; ++n) e2cur[n] = e2g[n * 16 + l15];

    STAGE(0, 0);
    int cur = 0;

#pragma unroll 1
    for (int ch = 0; ch < 16; ++ch) {
        int cb = ch * 64;
        __syncthreads();                    // drains vmcnt -> lds[cur] ready
        if (ch < 15) STAGE(cur ^ 1, ch + 1);

        float e2nxt[4];
        if (ch < 15) {
#pragma unroll
            for (int n = 0; n < 4; ++n) e2nxt[n] = e2g[cb + 64 + n * 16 + l15];
        }

        f32x4 acc[2][4];
#pragma unroll
        for (int m = 0; m < 2; ++m)
#pragma unroll
            for (int n = 0; n < 4; ++n)
                acc[m][n] = (f32x4){-e2cur[n], -e2cur[n], -e2cur[n], -e2cur[n]};

#pragma unroll
        for (int c = 0; c < 2; ++c) {
            bf16x8 bh[4], bl[4];
            int base = (c * 4 + l4) * 512 + l15 * 8;
#pragma unroll
            for (int n = 0; n < 4; ++n) {
                bh[n] = *reinterpret_cast<const bf16x8*>(&lds[cur][base + n * 128]);
                bl[n] = *reinterpret_cast<const bf16x8*>(&lds[cur][4096 + base + n * 128]);
            }
#pragma unroll
            for (int m = 0; m < 2; ++m)
#pragma unroll
                for (int n = 0; n < 4; ++n) {
                    acc[m][n] = __builtin_amdgcn_mfma_f32_16x16x32_bf16(ah[m][c], bh[n], acc[m][n], 0, 0, 0);
                    acc[m][n] = __builtin_amdgcn_mfma_f32_16x16x32_bf16(ah[m][c], bl[n], acc[m][n], 0, 0, 0);
                    acc[m][n] = __builtin_amdgcn_mfma_f32_16x16x32_bf16(al[m][c], bh[n], acc[m][n], 0, 0, 0);
                }
        }

#pragma unroll
        for (int n = 0; n < 4; ++n) {
            int col = cb + n * 16 + l15;
#pragma unroll
            for (int m = 0; m < 2; ++m)
#pragma unroll
                for (int r = 0; r < 4; ++r) {
                    float s = acc[m][n][r];
                    bool gt = s > m1[m][r];
                    m2[m][r] = __builtin_amdgcn_fmed3f(s, m1[m][r], m2[m][r]);
                    k1[m][r] = gt ? col : k1[m][r];
                    m1[m][r] = fmaxf(m1[m][r], s);
                }
        }
#pragma unroll
        for (int n = 0; n < 4; ++n) e2cur[n] = e2nxt[n];
        cur ^= 1;
    }
#undef STAGE

    int* ckk = reinterpret_cast<int*>(&lds[0][0]);   // overlays dead buf0

#pragma unroll
    for (int m = 0; m < 2; ++m)
#pragma unroll
        for (int r = 0; r < 4; ++r) {
            float a1 = m1[m][r], a2 = m2[m][r];
            int ak = k1[m][r];
#pragma unroll
            for (int d = 1; d < 16; d <<= 1) {
                float o1 = __shfl_xor(a1, d, 64);
                float o2 = __shfl_xor(a2, d, 64);
                int   ok = __shfl_xor(ak, d, 64);
                bool sw = (o1 > a1) || (o1 == a1 && ok < ak);
                float big = sw ? o1 : a1;
                int bigk = sw ? ok : ak;
                float small = sw ? a1 : o1;
                a2 = fmaxf(fmaxf(a2, o2), small);
                a1 = big; ak = bigk;
            }
            if (l15 == 0) {
                int rloc = m * 16 + l4 * 4 + r;
                int row = n0 + wid * 32 + rloc;
                ckk[wid * 32 + rloc] = ak;
                ind_t[(size_t)g * NQ + row] = ak;
                if (a1 - a2 < MARGIN) {
                    int idx = atomicAdd(ctr, 1);
                    if (idx < CAP) list[idx] = make_int2(row, g);
                }
            }
        }
    __syncthreads();

    if (lane < 32) {
        int row = n0 + wid * 32 + lane;
        ind_out[(size_t)row * GQ + g] = (float)ckk[wid * 32 + lane];
    }
#pragma unroll 4
    for (int rr = 0; rr < 32; ++rr) {
        int k = ckk[wid * 32 + rr];
        float v = embed[((size_t)(g * KQ + k)) * dq + lane];
        zq[(size_t)(n0 + wid * 32 + rr) * DQ + g * dq + lane] = v;
    }
}

// ---- f64 recheck (separate, load-balanced, vectorized) ----
__launch_bounds__(256)
__global__ void k_recheck(const float* __restrict__ x, const float* __restrict__ embed,
                          const double* __restrict__ e2d,
                          const int* __restrict__ ctr, const int2* __restrict__ list,
                          int* __restrict__ ind_t, float* __restrict__ zq,
                          float* __restrict__ ind_out) {
    __shared__ double sv[256];
    __shared__ int si[256];
    int nitems = *ctr;
    if (nitems > CAP) nitems = CAP;
    for (int it = blockIdx.x; it < nitems; it += gridDim.x) {
        int2 q = list[it];
        int n = q.x, g = q.y;
        const float4* xr4 = reinterpret_cast<const float4*>(x + (size_t)n * DQ + g * dq);
        float4 xr[16];
#pragma unroll
        for (int j = 0; j < 16; ++j) xr[j] = xr4[j];
        double best = -1e300;
        int bk = KQ;
        for (int k = threadIdx.x; k < KQ; k += 256) {
            const float4* er = reinterpret_cast<const float4*>(embed + ((size_t)g * KQ + k) * dq);
            double dot = 0.0;
#pragma unroll
            for (int j = 0; j < 16; ++j) {
                float4 e4 = er[j];
                dot = fma((double)xr[j].x, (double)e4.x, dot);
                dot = fma((double)xr[j].y, (double)e4.y, dot);
                dot = fma((double)xr[j].z, (double)e4.z, dot);
                dot = fma((double)xr[j].w, (double)e4.w, dot);
            }
            double s = 2.0 * dot - e2d[g * KQ + k];
            if (s > best || (s == best && k < bk)) { best = s; bk = k; }
        }
        sv[threadIdx.x] = best; si[threadIdx.x] = bk;
        __syncthreads();
        for (int off = 128; off > 0; off >>= 1) {
            if (threadIdx.x < off) {
                double ov = sv[threadIdx.x + off]; int oi = si[threadIdx.x + off];
                if (ov > sv[threadIdx.x] || (ov == sv[threadIdx.x] && oi < si[threadIdx.x])) {
                    sv[threadIdx.x] = ov; si[threadIdx.x] = oi;
                }
            }
            __syncthreads();
        }
        int kbest = si[0];
        if (threadIdx.x == 0) {
            ind_t[(size_t)g * NQ + n] = kbest;
            ind_out[(size_t)n * GQ + g] = (float)kbest;
        }
        if (threadIdx.x < dq)
            zq[(size_t)n * DQ + g * dq + threadIdx.x] =
                embed[((size_t)g * KQ + kbest) * dq + threadIdx.x];
        __syncthreads();
    }
}

// ---- segsum v4b: 32 bins/block, 8-way N-split, 4-batched drain (R17, proven) ----
#define SBINS 32
__launch_bounds__(256)
__global__ void k_segsum4(const float* __restrict__ x, const int* __restrict__ ind_t,
                          int* __restrict__ partial, int* __restrict__ pcnt) {
    __shared__ int lacc[SBINS][64];   // 8 KB
    __shared__ int lcnt[SBINS];
    __shared__ int queue[4][128];

    int bid = blockIdx.x;             // [0,1024): g(2) | grp(5) | split(3)
    int g = bid >> 8;
    int grp = (bid >> 3) & 31;
    int split = bid & 7;
    int kbase = grp * SBINS;
    int tid = threadIdx.x, wid = tid >> 6, lane = tid & 63;

    for (int i = tid; i < SBINS * 64; i += 256) ((int*)lacc)[i] = 0;
    if (tid < SBINS) lcnt[tid] = 0;
    __syncthreads();

    const int* ip = ind_t + (size_t)g * NQ;
    const float* xg = x + g * dq;
    int nbase = split * 4096 + wid * 1024;
    int wqn = 0;

#define DRAIN4                                                                      \
    do {                                                                            \
        int nq4 = wqn & ~3;                                                         \
        for (int q = 0; q < nq4; q += 4) {                                          \
            int ea = queue[wid][q],     eb = queue[wid][q + 1];                     \
            int ec = queue[wid][q + 2], ed = queue[wid][q + 3];                     \
            float va = xg[(size_t)(ea & 0xfffff) * DQ + lane];                      \
            float vb = xg[(size_t)(eb & 0xfffff) * DQ + lane];                      \
            float vc = xg[(size_t)(ec & 0xfffff) * DQ + lane];                      \
            float vd = xg[(size_t)(ed & 0xfffff) * DQ + lane];                      \
            atomicAdd(&lacc[ea >> 20][lane], __float2int_rn(va * FPS));             \
            atomicAdd(&lacc[eb >> 20][lane], __float2int_rn(vb * FPS));             \
            atomicAdd(&lacc[ec >> 20][lane], __float2int_rn(vc * FPS));             \
            atomicAdd(&lacc[ed >> 20][lane], __float2int_rn(vd * FPS));             \
            if (lane == 0) {                                                        \
                atomicAdd(&lcnt[ea >> 20], 1); atomicAdd(&lcnt[eb >> 20], 1);       \
                atomicAdd(&lcnt[ec >> 20], 1); atomicAdd(&lcnt[ed >> 20], 1);       \
            }                                                                       \
        }                                                                           \
        for (int q = nq4; q < wqn; ++q) {                                           \
            int e = queue[wid][q];                                                  \
            float v = xg[(size_t)(e & 0xfffff) * DQ + lane];                        \
            atomicAdd(&lacc[e >> 20][lane], __float2int_rn(v * FPS));               \
            if (lane == 0) atomicAdd(&lcnt[e >> 20], 1);                            \
        }                                                                           \
        wqn = 0;                                                                    \
    } while (0)

    for (int c = 0; c < 1024; c += 64) {
        int n = nbase + c + lane;
        int d = ip[n] - kbase;
        bool hit = (unsigned)d < (unsigned)SBINS;
        unsigned long long mask = __ballot(hit);
        if (hit) {
            int pos = wqn + __popcll(mask & ((1ull << lane) - 1ull));
            queue[wid][pos] = (d << 20) | n;
        }
        wqn += __popcll(mask);
        if (wqn >= 64) DRAIN4;
    }
    DRAIN4;
#undef DRAIN4
    __syncthreads();

    int base = split * (GQ * KQ) + g * KQ + kbase;
    for (int i = tid; i < SBINS * 64; i += 256) {
        int b = i >> 6, l = i & 63;
        partial[(size_t)(base + b) * 64 + l] = lacc[b][l];
    }
    if (tid < SBINS) pcnt[base + tid] = lcnt[tid];
}

// ---- final: combine 8 partials; out_cs / out_avg / out_embed ----
__global__ void k_final(const int* __restrict__ partial, const int* __restrict__ pcnt,
                        const float* __restrict__ embed_avg, const float* __restrict__ cs,
                        const float* __restrict__ tot,
                        float* __restrict__ out_cs, float* __restrict__ out_avg,
                        float* __restrict__ out_embed) {
    int t = blockIdx.x * 256 + threadIdx.x;   // 0..262143
    int gk = t >> 6, l = t & 63, g = gk >> 10;
    const int GK = GQ * KQ;
    int s = 0, c = 0;
#pragma unroll
    for (int sp = 0; sp < 8; ++sp) {
        s += partial[((size_t)sp * GK + gk) * 64 + l];
        c += pcnt[sp * GK + gk];
    }
    float a = (float)s * (1.0f / FPS);
    float nea = DECAYF * embed_avg[t] + (1.0f - DECAYF) * a;
    out_avg[t] = nea;
    float ncs = DECAYF * cs[gk] + (1.0f - DECAYF) * (float)c;
    if (l == 0) out_cs[gk] = ncs;
    double tt = (double)tot[g];
    double sm = ((double)ncs + (double)EPSF) / (tt + (double)KQ * (double)EPSF) * tt;
    out_embed[t] = nea / (float)sm;
}

extern "C" void kernel_launch(void* const* d_in, const int* in_sizes, int n_in,
                              void* d_out, int out_size, void* d_ws, size_t ws_size,
                              hipStream_t stream) {
    const float* x         = (const float*)d_in[0];
    const float* embed     = (const float*)d_in[1];
    const float* embed_avg = (const float*)d_in[2];
    const float* cs        = (const float*)d_in[3];
    float* out = (float*)d_out;
    float* zq        = out + OFF_ZQ;
    float* ind_out   = out + OFF_IND;
    float* out_embed = out + OFF_EMB;
    float* out_cs    = out + OFF_CS;
    float* out_avg   = out + OFF_AVG;

    char* ws = (char*)d_ws;
    int*    ind_t = (int*)(ws + WS_IND);
    float*  e2    = (float*)(ws + WS_E2);
    ushort* eh    = (ushort*)(ws + WS_EH);
    ushort* el    = (ushort*)(ws + WS_EL);
    int*    ctr   = (int*)(ws + WS_CTR);
    int2*   list  = (int2*)(ws + WS_LIST);
    double* e2d   = (double*)(ws + WS_E2D);
    float*  tot   = (float*)(ws + WS_TOT);
    int*    part  = (int*)(ws + WS_PART);
    int*    pcnt  = (int*)(ws + WS_PCNT);

    k_prep<<<128, 256, 0, stream>>>(embed, cs, e2, e2d, eh, el, tot, ctr);
    dim3 g1(NQ / MBLK, GQ);
    k_scores_mfma<<<g1, 256, 0, stream>>>(x, eh, el, e2, embed, ind_t, zq, ind_out, ctr, list);
    k_recheck<<<256, 256, 0, stream>>>(x, embed, e2d, ctr, list, ind_t, zq, ind_out);
    k_segsum4<<<1024, 256, 0, stream>>>(x, ind_t, part, pcnt);
    k_final<<<(GQ * KQ * dq) / 256, 256, 0, stream>>>(part, pcnt, embed_avg, cs, tot,
                                                      out_cs, out_avg, out_embed);
}

// Round 23
// 121.024 us; speedup vs baseline: 1.1171x; 1.0296x over previous
//
#include <hip/hip_runtime.h>
#include <cstdint>

// Problem constants
#define GQ 4
#define KQ 1024
#define DQ 256     // = GQ * dq
#define dq 64
#define NQ 32768   // B*S = 8*4096
#define DECAYF 0.99f
#define EPSF 1e-5f

// Output flat offsets (floats)
#define OFF_ZQ    0
#define OFF_IND   8388608
#define OFF_EMB   8519680
#define OFF_CS    8781824
#define OFF_AVG   8785920

// Workspace layout (bytes)
#define WS_IND   0              // int32 [GQ][NQ]  (transposed ind)
#define WS_E2    524288         // float [GQ][KQ]
#define WS_EH    540672         // ushort(bf16) fragment-ordered embed hi
#define WS_EL    1064960        // ushort(bf16) fragment-ordered embed lo
#define WS_CTR   1589264        // int
#define WS_LIST  1589280        // int2 [CAP]
#define CAP      16384
#define WS_E2D   1720352        // double [GQ*KQ]
#define WS_TOT   1753120        // float [GQ]
#define WS_PART  1753344        // int32 [8][GQ*KQ][64] partial fixed-point sums (8 MB)
#define WS_PCNT  10141952       // int32 [8][GQ*KQ] partial counts (128 KB)

#define MARGIN 0.01f
#define FPS 65536.0f            // 2^16 fixed-point (order-free exact adds)

#define MBLK 128   // rows per block (4 waves x 32 rows) — R17/R20/R22-verified

typedef __attribute__((ext_vector_type(8))) short bf16x8;
typedef __attribute__((ext_vector_type(4))) float f32x4;

// f32 -> bf16 hi/lo split of 8 values, scaled by 2 (exact exponent shift)
__device__ __forceinline__ void split8_2x(float4 u, float4 v, bf16x8& h, bf16x8& l) {
    float f[8] = {u.x, u.y, u.z, u.w, v.x, v.y, v.z, v.w};
#pragma unroll
    for (int j = 0; j < 8; ++j) {
        float s = f[j] * 2.0f;
        uint32_t b = __float_as_uint(s);
        uint32_t hb = b & 0xffff0000u;
        float r = s - __uint_as_float(hb);
        uint32_t rb = __float_as_uint(r);
        h[j] = (short)(hb >> 16);
        l[j] = (short)((rb + 0x7fffu + ((rb >> 16) & 1u)) >> 16);
    }
}

// ---- prep: e2 (f32+f64); embed split bf16 hi/lo FRAGMENT ORDER; tot[g]; ctr=0 ----
__global__ void k_prep(const float* __restrict__ embed, const float* __restrict__ cs,
                       float* __restrict__ e2, double* __restrict__ e2d,
                       ushort* __restrict__ eh, ushort* __restrict__ el,
                       float* __restrict__ tot, int* __restrict__ ctr) {
    __shared__ double red[256];
    int t = blockIdx.x * 256 + threadIdx.x;   // 0..32767
    int row = t >> 3;                         // g*1024 + k
    int f = t & 7;
    int c = f >> 2, l4 = f & 3;
    int g = row >> 10, k = row & 1023;
    int ch = k >> 6, co = k & 63;

    const float4* p = reinterpret_cast<const float4*>(embed + (size_t)row * dq + f * 8);
    float4 u = p[0], v = p[1];
    float fv[8] = {u.x, u.y, u.z, u.w, v.x, v.y, v.z, v.w};
    bf16x8 h, l;
    double s = 0.0;
#pragma unroll
    for (int jj = 0; jj < 8; ++jj) {
        float x = fv[jj];
        s = fma((double)x, (double)x, s);
        uint32_t b = __float_as_uint(x);
        uint32_t hb = (b + 0x7fffu + ((b >> 16) & 1u)) & 0xffff0000u;
        float r = x - __uint_as_float(hb);
        uint32_t rb = __float_as_uint(r);
        h[jj] = (short)(hb >> 16);
        l[jj] = (short)((rb + 0x7fffu + ((rb >> 16) & 1u)) >> 16);
    }
    size_t addr = (size_t)g * 65536 + (size_t)ch * 4096 + (size_t)(c * 4 + l4) * 512 + co * 8;
    *reinterpret_cast<bf16x8*>(eh + addr) = h;
    *reinterpret_cast<bf16x8*>(el + addr) = l;
    s += __shfl_xor(s, 1, 64);
    s += __shfl_xor(s, 2, 64);
    s += __shfl_xor(s, 4, 64);
    if (f == 0) { e2[row] = (float)s; e2d[row] = s; }

    if (blockIdx.x < 4) {
        int gg = blockIdx.x;
        const float4* c4 = reinterpret_cast<const float4*>(cs + gg * KQ);
        float4 cv = c4[threadIdx.x];
        red[threadIdx.x] = (double)cv.x + (double)cv.y + (double)cv.z + (double)cv.w;
        __syncthreads();
        for (int off = 128; off > 0; off >>= 1) {
            if (threadIdx.x < off) red[threadIdx.x] += red[threadIdx.x + off];
            __syncthreads();
        }
        if (threadIdx.x == 0) {
            tot[gg] = (float)((double)DECAYF * red[0] + (1.0 - (double)DECAYF) * (double)NQ);
            if (gg == 0) *ctr = 0;
        }
    }
}

// ---- MFMA scores (R17/R20/R22-verified): LDS dbuf staging + fused argmax + zq/ind ----
__launch_bounds__(256)
__global__ void k_scores_mfma(const float* __restrict__ x,
                              const ushort* __restrict__ eh,
                              const ushort* __restrict__ el,
                              const float* __restrict__ e2,
                              const float* __restrict__ embed,
                              int* __restrict__ ind_t,
                              float* __restrict__ zq,
                              float* __restrict__ ind_out,
                              int* __restrict__ ctr, int2* __restrict__ list) {
    int g = blockIdx.y;
    int n0 = blockIdx.x * MBLK;
    int tid = threadIdx.x;
    int wid = tid >> 6;          // 0..3
    int lane = tid & 63;
    int l15 = lane & 15, l4 = lane >> 4;

    __shared__ ushort lds[2][8192];   // 32 KB; ckk overlays buf0 post-loop

    bf16x8 ah[2][2], al[2][2];
#pragma unroll
    for (int m = 0; m < 2; ++m)
#pragma unroll
        for (int c = 0; c < 2; ++c) {
            const float4* p = reinterpret_cast<const float4*>(
                x + (size_t)(n0 + wid * 32 + m * 16 + l15) * DQ + g * dq + c * 32 + l4 * 8);
            split8_2x(p[0], p[1], ah[m][c], al[m][c]);
        }

    const ushort* ehg = eh + (size_t)g * 65536;
    const ushort* elg = el + (size_t)g * 65536;
    const float*  e2g = e2 + (size_t)g * KQ;

    float m1[2][4], m2[2][4];
    int   k1[2][4];
#pragma unroll
    for (int m = 0; m < 2; ++m)
#pragma unroll
        for (int r = 0; r < 4; ++r) { m1[m][r] = -3.4e38f; m2[m][r] = -3.4e38f; k1[m][r] = 0; }

    int wu = wid * 512;
#define STAGE(b, ch)                                                               \
    do {                                                                           \
        const ushort* s0_ = ehg + (ch) * 4096 + tid * 8;                           \
        const ushort* s1_ = elg + (ch) * 4096 + tid * 8;                           \
        __builtin_amdgcn_global_load_lds(s0_,        &lds[b][wu],        16, 0, 0);\
        __builtin_amdgcn_global_load_lds(s0_ + 2048, &lds[b][2048 + wu], 16, 0, 0);\
        __builtin_amdgcn_global_load_lds(s1_,        &lds[b][4096 + wu], 16, 0, 0);\
        __builtin_amdgcn_global_load_lds(s1_ + 2048, &lds[b][6144 + wu], 16, 0, 0);\
    } while (0)

    float e2cur[4];
#pragma unroll
    for (int n = 0; n < 4; ++n) e2cur[n] = e2g[n * 16 + l15];

    STAGE(0, 0);
    int cur = 0;

#pragma unroll 1
    for (int ch = 0; ch < 16; ++ch) {
        int cb = ch * 64;
        __syncthreads();                    // drains vmcnt -> lds[cur] ready
        if (ch < 15) STAGE(cur ^ 1, ch + 1);

        float e2nxt[4];
        if (ch < 15) {
#pragma unroll
            for (int n = 0; n < 4; ++n) e2nxt[n] = e2g[cb + 64 + n * 16 + l15];
        }

        f32x4 acc[2][4];
#pragma unroll
        for (int m = 0; m < 2; ++m)
#pragma unroll
            for (int n = 0; n < 4; ++n)
                acc[m][n] = (f32x4){-e2cur[n], -e2cur[n], -e2cur[n], -e2cur[n]};

#pragma unroll
        for (int c = 0; c < 2; ++c) {
            bf16x8 bh[4], bl[4];
            int base = (c * 4 + l4) * 512 + l15 * 8;
#pragma unroll
            for (int n = 0; n < 4; ++n) {
                bh[n] = *reinterpret_cast<const bf16x8*>(&lds[cur][base + n * 128]);
                bl[n] = *reinterpret_cast<const bf16x8*>(&lds[cur][4096 + base + n * 128]);
            }
#pragma unroll
            for (int m = 0; m < 2; ++m)
#pragma unroll
                for (int n = 0; n < 4; ++n) {
                    acc[m][n] = __builtin_amdgcn_mfma_f32_16x16x32_bf16(ah[m][c], bh[n], acc[m][n], 0, 0, 0);
                    acc[m][n] = __builtin_amdgcn_mfma_f32_16x16x32_bf16(ah[m][c], bl[n], acc[m][n], 0, 0, 0);
                    acc[m][n] = __builtin_amdgcn_mfma_f32_16x16x32_bf16(al[m][c], bh[n], acc[m][n], 0, 0, 0);
                }
        }

#pragma unroll
        for (int n = 0; n < 4; ++n) {
            int col = cb + n * 16 + l15;
#pragma unroll
            for (int m = 0; m < 2; ++m)
#pragma unroll
                for (int r = 0; r < 4; ++r) {
                    float s = acc[m][n][r];
                    bool gt = s > m1[m][r];
                    m2[m][r] = __builtin_amdgcn_fmed3f(s, m1[m][r], m2[m][r]);
                    k1[m][r] = gt ? col : k1[m][r];
                    m1[m][r] = fmaxf(m1[m][r], s);
                }
        }
#pragma unroll
        for (int n = 0; n < 4; ++n) e2cur[n] = e2nxt[n];
        cur ^= 1;
    }
#undef STAGE

    int* ckk = reinterpret_cast<int*>(&lds[0][0]);   // overlays dead buf0

#pragma unroll
    for (int m = 0; m < 2; ++m)
#pragma unroll
        for (int r = 0; r < 4; ++r) {
            float a1 = m1[m][r], a2 = m2[m][r];
            int ak = k1[m][r];
#pragma unroll
            for (int d = 1; d < 16; d <<= 1) {
                float o1 = __shfl_xor(a1, d, 64);
                float o2 = __shfl_xor(a2, d, 64);
                int   ok = __shfl_xor(ak, d, 64);
                bool sw = (o1 > a1) || (o1 == a1 && ok < ak);
                float big = sw ? o1 : a1;
                int bigk = sw ? ok : ak;
                float small = sw ? a1 : o1;
                a2 = fmaxf(fmaxf(a2, o2), small);
                a1 = big; ak = bigk;
            }
            if (l15 == 0) {
                int rloc = m * 16 + l4 * 4 + r;
                int row = n0 + wid * 32 + rloc;
                ckk[wid * 32 + rloc] = ak;
                ind_t[(size_t)g * NQ + row] = ak;
                if (a1 - a2 < MARGIN) {
                    int idx = atomicAdd(ctr, 1);
                    if (idx < CAP) list[idx] = make_int2(row, g);
                }
            }
        }
    __syncthreads();

    if (lane < 32) {
        int row = n0 + wid * 32 + lane;
        ind_out[(size_t)row * GQ + g] = (float)ckk[wid * 32 + lane];
    }
#pragma unroll 4
    for (int rr = 0; rr < 32; ++rr) {
        int k = ckk[wid * 32 + rr];
        float v = embed[((size_t)(g * KQ + k)) * dq + lane];
        zq[(size_t)(n0 + wid * 32 + rr) * DQ + g * dq + lane] = v;
    }
}

// ---- f64 recheck (512 blocks: halves per-block serial item count) ----
__launch_bounds__(256)
__global__ void k_recheck(const float* __restrict__ x, const float* __restrict__ embed,
                          const double* __restrict__ e2d,
                          const int* __restrict__ ctr, const int2* __restrict__ list,
                          int* __restrict__ ind_t, float* __restrict__ zq,
                          float* __restrict__ ind_out) {
    __shared__ double sv[256];
    __shared__ int si[256];
    int nitems = *ctr;
    if (nitems > CAP) nitems = CAP;
    for (int it = blockIdx.x; it < nitems; it += gridDim.x) {
        int2 q = list[it];
        int n = q.x, g = q.y;
        const float4* xr4 = reinterpret_cast<const float4*>(x + (size_t)n * DQ + g * dq);
        float4 xr[16];
#pragma unroll
        for (int j = 0; j < 16; ++j) xr[j] = xr4[j];
        double best = -1e300;
        int bk = KQ;
        for (int k = threadIdx.x; k < KQ; k += 256) {
            const float4* er = reinterpret_cast<const float4*>(embed + ((size_t)g * KQ + k) * dq);
            double dot = 0.0;
#pragma unroll
            for (int j = 0; j < 16; ++j) {
                float4 e4 = er[j];
                dot = fma((double)xr[j].x, (double)e4.x, dot);
                dot = fma((double)xr[j].y, (double)e4.y, dot);
                dot = fma((double)xr[j].z, (double)e4.z, dot);
                dot = fma((double)xr[j].w, (double)e4.w, dot);
            }
            double s = 2.0 * dot - e2d[g * KQ + k];
            if (s > best || (s == best && k < bk)) { best = s; bk = k; }
        }
        sv[threadIdx.x] = best; si[threadIdx.x] = bk;
        __syncthreads();
        for (int off = 128; off > 0; off >>= 1) {
            if (threadIdx.x < off) {
                double ov = sv[threadIdx.x + off]; int oi = si[threadIdx.x + off];
                if (ov > sv[threadIdx.x] || (ov == sv[threadIdx.x] && oi < si[threadIdx.x])) {
                    sv[threadIdx.x] = ov; si[threadIdx.x] = oi;
                }
            }
            __syncthreads();
        }
        int kbest = si[0];
        if (threadIdx.x == 0) {
            ind_t[(size_t)g * NQ + n] = kbest;
            ind_out[(size_t)n * GQ + g] = (float)kbest;
        }
        if (threadIdx.x < dq)
            zq[(size_t)n * DQ + g * dq + threadIdx.x] =
                embed[((size_t)g * KQ + kbest) * dq + threadIdx.x];
        __syncthreads();
    }
}

// ---- segsum v4b: 32 bins/block, 8-way N-split, 4-batched drain (R17, proven) ----
#define SBINS 32
__launch_bounds__(256)
__global__ void k_segsum4(const float* __restrict__ x, const int* __restrict__ ind_t,
                          int* __restrict__ partial, int* __restrict__ pcnt) {
    __shared__ int lacc[SBINS][64];   // 8 KB
    __shared__ int lcnt[SBINS];
    __shared__ int queue[4][128];

    int bid = blockIdx.x;             // [0,1024): g(2) | grp(5) | split(3)
    int g = bid >> 8;
    int grp = (bid >> 3) & 31;
    int split = bid & 7;
    int kbase = grp * SBINS;
    int tid = threadIdx.x, wid = tid >> 6, lane = tid & 63;

    for (int i = tid; i < SBINS * 64; i += 256) ((int*)lacc)[i] = 0;
    if (tid < SBINS) lcnt[tid] = 0;
    __syncthreads();

    const int* ip = ind_t + (size_t)g * NQ;
    const float* xg = x + g * dq;
    int nbase = split * 4096 + wid * 1024;
    int wqn = 0;

#define DRAIN4                                                                      \
    do {                                                                            \
        int nq4 = wqn & ~3;                                                         \
        for (int q = 0; q < nq4; q += 4) {                                          \
            int ea = queue[wid][q],     eb = queue[wid][q + 1];                     \
            int ec = queue[wid][q + 2], ed = queue[wid][q + 3];                     \
            float va = xg[(size_t)(ea & 0xfffff) * DQ + lane];                      \
            float vb = xg[(size_t)(eb & 0xfffff) * DQ + lane];                      \
            float vc = xg[(size_t)(ec & 0xfffff) * DQ + lane];                      \
            float vd = xg[(size_t)(ed & 0xfffff) * DQ + lane];                      \
            atomicAdd(&lacc[ea >> 20][lane], __float2int_rn(va * FPS));             \
            atomicAdd(&lacc[eb >> 20][lane], __float2int_rn(vb * FPS));             \
            atomicAdd(&lacc[ec >> 20][lane], __float2int_rn(vc * FPS));             \
            atomicAdd(&lacc[ed >> 20][lane], __float2int_rn(vd * FPS));             \
            if (lane == 0) {                                                        \
                atomicAdd(&lcnt[ea >> 20], 1); atomicAdd(&lcnt[eb >> 20], 1);       \
                atomicAdd(&lcnt[ec >> 20], 1); atomicAdd(&lcnt[ed >> 20], 1);       \
            }                                                                       \
        }                                                                           \
        for (int q = nq4; q < wqn; ++q) {                                           \
            int e = queue[wid][q];                                                  \
            float v = xg[(size_t)(e & 0xfffff) * DQ + lane];                        \
            atomicAdd(&lacc[e >> 20][lane], __float2int_rn(v * FPS));               \
            if (lane == 0) atomicAdd(&lcnt[e >> 20], 1);                            \
        }                                                                           \
        wqn = 0;                                                                    \
    } while (0)

    for (int c = 0; c < 1024; c += 64) {
        int n = nbase + c + lane;
        int d = ip[n] - kbase;
        bool hit = (unsigned)d < (unsigned)SBINS;
        unsigned long long mask = __ballot(hit);
        if (hit) {
            int pos = wqn + __popcll(mask & ((1ull << lane) - 1ull));
            queue[wid][pos] = (d << 20) | n;
        }
        wqn += __popcll(mask);
        if (wqn >= 64) DRAIN4;
    }
    DRAIN4;
#undef DRAIN4
    __syncthreads();

    int base = split * (GQ * KQ) + g * KQ + kbase;
    for (int i = tid; i < SBINS * 64; i += 256) {
        int b = i >> 6, l = i & 63;
        partial[(size_t)(base + b) * 64 + l] = lacc[b][l];
    }
    if (tid < SBINS) pcnt[base + tid] = lcnt[tid];
}

// ---- final: combine 8 partials; out_cs / out_avg / out_embed ----
__global__ void k_final(const int* __restrict__ partial, const int* __restrict__ pcnt,
                        const float* __restrict__ embed_avg, const float* __restrict__ cs,
                        const float* __restrict__ tot,
                        float* __restrict__ out_cs, float* __restrict__ out_avg,
                        float* __restrict__ out_embed) {
    int t = blockIdx.x * 256 + threadIdx.x;   // 0..262143
    int gk = t >> 6, l = t & 63, g = gk >> 10;
    const int GK = GQ * KQ;
    int s = 0, c = 0;
#pragma unroll
    for (int sp = 0; sp < 8; ++sp) {
        s += partial[((size_t)sp * GK + gk) * 64 + l];
        c += pcnt[sp * GK + gk];
    }
    float a = (float)s * (1.0f / FPS);
    float nea = DECAYF * embed_avg[t] + (1.0f - DECAYF) * a;
    out_avg[t] = nea;
    float ncs = DECAYF * cs[gk] + (1.0f - DECAYF) * (float)c;
    if (l == 0) out_cs[gk] = ncs;
    double tt = (double)tot[g];
    double sm = ((double)ncs + (double)EPSF) / (tt + (double)KQ * (double)EPSF) * tt;
    out_embed[t] = nea / (float)sm;
}

extern "C" void kernel_launch(void* const* d_in, const int* in_sizes, int n_in,
                              void* d_out, int out_size, void* d_ws, size_t ws_size,
                              hipStream_t stream) {
    const float* x         = (const float*)d_in[0];
    const float* embed     = (const float*)d_in[1];
    const float* embed_avg = (const float*)d_in[2];
    const float* cs        = (const float*)d_in[3];
    float* out = (float*)d_out;
    float* zq        = out + OFF_ZQ;
    float* ind_out   = out + OFF_IND;
    float* out_embed = out + OFF_EMB;
    float* out_cs    = out + OFF_CS;
    float* out_avg   = out + OFF_AVG;

    char* ws = (char*)d_ws;
    int*    ind_t = (int*)(ws + WS_IND);
    float*  e2    = (float*)(ws + WS_E2);
    ushort* eh    = (ushort*)(ws + WS_EH);
    ushort* el    = (ushort*)(ws + WS_EL);
    int*    ctr   = (int*)(ws + WS_CTR);
    int2*   list  = (int2*)(ws + WS_LIST);
    double* e2d   = (double*)(ws + WS_E2D);
    float*  tot   = (float*)(ws + WS_TOT);
    int*    part  = (int*)(ws + WS_PART);
    int*    pcnt  = (int*)(ws + WS_PCNT);

    k_prep<<<128, 256, 0, stream>>>(embed, cs, e2, e2d, eh, el, tot, ctr);
    dim3 g1(NQ / MBLK, GQ);
    k_scores_mfma<<<g1, 256, 0, stream>>>(x, eh, el, e2, embed, ind_t, zq, ind_out, ctr, list);
    k_recheck<<<512, 256, 0, stream>>>(x, embed, e2d, ctr, list, ind_t, zq, ind_out);
    k_segsum4<<<1024, 256, 0, stream>>>(x, ind_t, part, pcnt);
    k_final<<<(GQ * KQ * dq) / 256, 256, 0, stream>>>(part, pcnt, embed_avg, cs, tot,
                                                      out_cs, out_avg, out_embed);
}